// Round 18
// baseline (369.890 us; speedup 1.0000x reference)
//
#include <hip/hip_runtime.h>
#include <hip/hip_bf16.h>
#include <hip/hip_cooperative_groups.h>

namespace cg = cooperative_groups;

// Sizes fixed by the problem
#define B2      2
#define NX      20000
#define F_IN    128
#define NS1     16000
#define ND1     8000
#define E1      100000
#define ND2     4000
#define E2      60000
#define HEADS   12
#define CH      128
#define K1      1536   // HEADS*CH
#define MROWS   (2*ND1) // 16000
#define CAP1    64
#define CAP2    64

typedef __bf16 bf16x8 __attribute__((ext_vector_type(8)));
typedef float  f32x4  __attribute__((ext_vector_type(4)));

static __device__ __forceinline__ float lrelu(float x) { return x > 0.f ? x : 0.2f * x; }

static __device__ __forceinline__ unsigned short f2bf(float f) {
    union { float f; unsigned u; } v; v.f = f;
    unsigned r = v.u + 0x7fffu + ((v.u >> 16) & 1u);
    return (unsigned short)(r >> 16);
}

// async global->LDS, 16 bytes per lane
static __device__ __forceinline__ void gld16(const void* g, void* l) {
    __builtin_amdgcn_global_load_lds(
        (const __attribute__((address_space(1))) unsigned int*)g,
        (__attribute__((address_space(3))) unsigned int*)l, 16, 0, 0);
}

// ===========================================================================
// Phase bodies (shared by cooperative and standalone kernels)
// ===========================================================================
static __device__ __forceinline__ void prep_body(
        int bx, int tid,
        const float* __restrict__ x, const int* __restrict__ n_id,
        const float* __restrict__ W, const float* __restrict__ asrc,
        const float* __restrict__ adst,
        unsigned short* __restrict__ xg, unsigned short* __restrict__ WT,
        unsigned short* __restrict__ wswd,
        int* __restrict__ dcnt, float* __restrict__ s2)
{
    if (bx < 4000) {
        int t = bx * 256 + tid;
        int row = t >> 5;
        int c4 = (t & 31) << 2;
        int b = row >= NS1 ? 1 : 0;
        int node = n_id[row - b * NS1];
        const float4 v = *reinterpret_cast<const float4*>(
            x + ((size_t)(b * NX + node)) * F_IN + c4);
        ushort4 o;
        o.x = f2bf(v.x); o.y = f2bf(v.y); o.z = f2bf(v.z); o.w = f2bf(v.w);
        *reinterpret_cast<ushort4*>(xg + (size_t)row * F_IN + c4) = o;
    } else if (bx < 4768) {
        int t = (bx - 4000) * 256 + tid;
        int k = t / K1;
        int n = t - k * K1;
        WT[(size_t)n * F_IN + k] = f2bf(W[t]);
    } else if (bx < 4784) {
        int t = (bx - 4768) * 256 + tid;
        int n = t >> 7;
        int c = t & 127;
        float acc = 0.f;
        if (n < 24) {
            int h = n < 12 ? n : n - 12;
            const float* att = (n < 12 ? asrc : adst) + h * CH;
            const float* wr = W + (size_t)c * K1 + h * CH;
            for (int j = 0; j < CH; ++j) acc += wr[j] * att[j];
        }
        wswd[(size_t)n * F_IN + c] = f2bf(acc);
    } else {
        int t = (bx - 4784) * 256 + tid;
        if (t < ND1 + ND2) dcnt[t] = 0;
        else if (t < ND1 + ND2 + MROWS) s2[t - (ND1 + ND2)] = 0.f;
    }
}

static __device__ __forceinline__ void escore_body(
        int vb, int tid,
        const unsigned short* __restrict__ xg,
        const unsigned short* __restrict__ wswd,
        float* __restrict__ es, float* __restrict__ ed)
{
    const int wave = tid >> 6, lane = tid & 63;
    const int l15 = lane & 15, l4 = lane >> 4;
    const int row0 = (vb * 4 + wave) * 16;
    const unsigned short* Ap = xg + (size_t)(row0 + l15) * F_IN + l4 * 8;

    f32x4 acc[2] = {f32x4{0,0,0,0}, f32x4{0,0,0,0}};
#pragma unroll
    for (int kk = 0; kk < 4; ++kk) {
        bf16x8 a = *reinterpret_cast<const bf16x8*>(Ap + kk * 32);
#pragma unroll
        for (int c = 0; c < 2; ++c) {
            bf16x8 b = *reinterpret_cast<const bf16x8*>(
                wswd + (size_t)(c * 16 + l15) * F_IN + kk * 32 + l4 * 8);
            acc[c] = __builtin_amdgcn_mfma_f32_16x16x32_bf16(a, b, acc[c], 0, 0, 0);
        }
    }
#pragma unroll
    for (int c = 0; c < 2; ++c) {
        int col = c * 16 + l15;
#pragma unroll
        for (int r = 0; r < 4; ++r) {
            int row = row0 + l4 * 4 + r;
            float v = acc[c][r];
            if (col < 12)       es[(size_t)row * HEADS + col] = v;
            else if (col < 24)  ed[(size_t)row * HEADS + (col - 12)] = v;
        }
    }
}

static __device__ __forceinline__ void scatter_body(
        int e,
        const int* __restrict__ dst1, const int* __restrict__ src1,
        const int* __restrict__ dst2, const int* __restrict__ src2,
        const int* __restrict__ res1,
        const float* __restrict__ es, const float* __restrict__ ed,
        int* __restrict__ dcnt, unsigned* __restrict__ ew,
        int* __restrict__ srcp2)
{
    if (e < E1) {
        int d = dst1[e];
        int k = atomicAdd(&dcnt[d], 1);
        if (k < CAP1) {
            int s = src1[e];
            int rd = res1[d];
#pragma unroll
            for (int b = 0; b < 2; ++b) {
                const float* esp = es + ((size_t)(b * NS1 + s)) * HEADS;
                const float* edp = ed + ((size_t)(b * NS1 + rd)) * HEADS;
                unsigned w[6];
#pragma unroll
                for (int j = 0; j < 6; ++j) {
                    float w0 = __expf(lrelu(esp[2 * j] + edp[2 * j]));
                    float w1 = __expf(lrelu(esp[2 * j + 1] + edp[2 * j + 1]));
                    w[j] = (unsigned)f2bf(w0) | ((unsigned)f2bf(w1) << 16);
                }
                unsigned* rp = ew + ((size_t)b * ND1 * CAP1 + (size_t)d * CAP1 + k) * 8;
                *reinterpret_cast<uint4*>(rp) = make_uint4((unsigned)s, w[0], w[1], w[2]);
                *reinterpret_cast<uint4*>(rp + 4) = make_uint4(w[3], w[4], w[5], 0u);
            }
        }
    } else if (e < E1 + E2) {
        int ee = e - E1;
        int d = dst2[ee];
        int k = atomicAdd(&dcnt[ND1 + d], 1);
        if (k < CAP2) srcp2[d * CAP2 + k] = src2[ee];
    }
}

static __device__ __forceinline__ void agg1_body(
        int vb, int tid,
        const unsigned short* __restrict__ xg,
        const unsigned* __restrict__ ew,
        const int* __restrict__ dcnt,
        unsigned short* __restrict__ agg)
{
    const int wv = tid >> 6, lane = tid & 63;
    const int task = vb * 4 + wv;
    const int b = task >= ND1 ? 1 : 0;
    const int i = task - b * ND1;
    const int c2 = lane * 2;

    const int deg = min(dcnt[i], CAP1);
    const uint4* eb = reinterpret_cast<const uint4*>(
        ew + ((size_t)b * ND1 * CAP1 + (size_t)i * CAP1) * 8);
    const unsigned short* xb = xg + (size_t)b * NS1 * F_IN + c2;

    float acc[24];
    float den[12];
#pragma unroll
    for (int r = 0; r < 24; ++r) acc[r] = 0.f;
#pragma unroll
    for (int h = 0; h < 12; ++h) den[h] = 0.f;

#pragma unroll 2
    for (int p = 0; p < deg; ++p) {
        uint4 r0 = eb[2 * p];
        uint4 r1 = eb[2 * p + 1];
        int se = (int)r0.x;
        unsigned xv = *reinterpret_cast<const unsigned*>(xb + (size_t)se * F_IN);
        float x0 = __uint_as_float(xv << 16);
        float x1 = __uint_as_float(xv & 0xffff0000u);
        unsigned wd[6] = {r0.y, r0.z, r0.w, r1.x, r1.y, r1.z};
#pragma unroll
        for (int j = 0; j < 6; ++j) {
            unsigned d = wd[j];
            float w0 = __uint_as_float(d << 16);
            float w1 = __uint_as_float(d & 0xffff0000u);
            acc[4 * j + 0] += w0 * x0; acc[4 * j + 1] += w0 * x1;
            acc[4 * j + 2] += w1 * x0; acc[4 * j + 3] += w1 * x1;
            den[2 * j]     += w0;      den[2 * j + 1] += w1;
        }
    }

    const size_t rowbase = ((size_t)(b * ND1 + i)) * K1;
#pragma unroll
    for (int j = 0; j < 12; ++j) {
        float r = 1.f / (den[j] + 1e-16f);
        unsigned pk = (unsigned)f2bf(acc[2 * j] * r) |
                      ((unsigned)f2bf(acc[2 * j + 1] * r) << 16);
        *reinterpret_cast<unsigned*>(agg + rowbase + j * CH + c2) = pk;
    }
}

static __device__ __forceinline__ void out1_body(
        int vb, int tid, unsigned short* As, unsigned short* Bs,
        const unsigned short* __restrict__ agg, const unsigned short* __restrict__ WT,
        const float* __restrict__ bias1, const float* __restrict__ W2,
        float* __restrict__ s2)
{
    const int wv = tid >> 6, lane = tid & 63;
    const int l15 = lane & 15, l4 = lane >> 4;
    const int h = vb / 125;
    const int row0 = (vb - h * 125) * 128;

    {
        const unsigned short* ga = agg + (size_t)row0 * K1 + h * CH;
        const unsigned short* gb = WT + (size_t)(h * CH) * F_IN;
#pragma unroll
        for (int p = 0; p < 8; ++p) {
            int r = p * 16 + wv * 4 + l4;
            int cs = l15 ^ (r & 7);
            gld16(ga + (size_t)r * K1 + cs * 8, As + (p * 16 + wv * 4) * 128);
            gld16(gb + (size_t)r * F_IN + cs * 8, Bs + (p * 16 + wv * 4) * 128);
        }
    }
    __syncthreads();

    f32x4 acc[2][8];
#pragma unroll
    for (int m = 0; m < 2; ++m)
#pragma unroll
        for (int c = 0; c < 8; ++c) acc[m][c] = f32x4{0, 0, 0, 0};

#pragma unroll
    for (int kk = 0; kk < 4; ++kk) {
        bf16x8 a[2];
#pragma unroll
        for (int m = 0; m < 2; ++m) {
            int r = wv * 32 + m * 16 + l15;
            int ch = (l4 + kk * 4) ^ (r & 7);
            a[m] = *reinterpret_cast<const bf16x8*>(As + r * 128 + ch * 8);
        }
#pragma unroll
        for (int c = 0; c < 8; ++c) {
            int n = c * 16 + l15;
            int ch = (l4 + kk * 4) ^ (n & 7);
            bf16x8 bb = *reinterpret_cast<const bf16x8*>(Bs + n * 128 + ch * 8);
#pragma unroll
            for (int m = 0; m < 2; ++m)
                acc[m][c] = __builtin_amdgcn_mfma_f32_16x16x32_bf16(a[m], bb,
                                                                    acc[m][c], 0, 0, 0);
        }
    }

#pragma unroll
    for (int m = 0; m < 2; ++m) {
        float part[4] = {0.f, 0.f, 0.f, 0.f};
#pragma unroll
        for (int c = 0; c < 8; ++c) {
            int n = h * CH + c * 16 + l15;
            float bi = bias1[n];
            float w2 = W2[n];
#pragma unroll
            for (int r = 0; r < 4; ++r) {
                float v = acc[m][c][r] + bi;
                v = v > 0.f ? v : 0.f;
                part[r] += v * w2;
            }
        }
#pragma unroll
        for (int r = 0; r < 4; ++r) {
#pragma unroll
            for (int o = 1; o < 16; o <<= 1) part[r] += __shfl_xor(part[r], o);
        }
        if (l15 == 0) {
            int row = row0 + wv * 32 + m * 16 + l4 * 4;
#pragma unroll
            for (int r = 0; r < 4; ++r)
                atomicAdd(&s2[row + r], part[r]);
        }
    }
    __syncthreads();   // protect LDS before any restage
}

static __device__ __forceinline__ void agg2_body(
        int t,
        const float* __restrict__ s2, const int* __restrict__ dcnt2,
        const int* __restrict__ srcp2, const int* __restrict__ res2,
        const float* __restrict__ asrc, const float* __restrict__ adst,
        const float* __restrict__ bias2, float* __restrict__ out)
{
    if (t >= 2 * ND2) return;
    int b = t / ND2, j = t - b * ND2;
    float a_s = asrc[0], a_d = adst[0];
    float edl = s2[(size_t)b * ND1 + res2[j]] * a_d;
    int deg = min(dcnt2[j], CAP2);
    float den = 0.f, num = 0.f;
    for (int k = 0; k < deg; ++k) {
        int s = srcp2[j * CAP2 + k];
        float v = s2[b * ND1 + s];
        float w = __expf(lrelu(v * a_s + edl));
        den += w;
        num += w * v;
    }
    float o = (deg > 0) ? num / (den + 1e-16f) : 0.f;
    out[(size_t)b * ND2 + j] = o + bias2[0];
}

// ===========================================================================
// Cooperative kernels
// ===========================================================================
__global__ __launch_bounds__(256, 4) void k_coopA(
        const float* __restrict__ x, const int* __restrict__ n_id,
        const float* __restrict__ W, const float* __restrict__ asrc,
        const float* __restrict__ adst,
        const int* __restrict__ src1, const int* __restrict__ dst1,
        const int* __restrict__ src2, const int* __restrict__ dst2,
        const int* __restrict__ res1,
        unsigned short* __restrict__ xg, unsigned short* __restrict__ WT,
        unsigned short* __restrict__ wswd,
        int* __restrict__ dcnt, float* __restrict__ s2,
        float* __restrict__ es, float* __restrict__ ed,
        unsigned* __restrict__ ew, int* __restrict__ srcp2,
        unsigned short* __restrict__ agg)
{
    cg::grid_group grid = cg::this_grid();
    const int tid = threadIdx.x;
    const int nb = gridDim.x;

    for (int bx = blockIdx.x; bx < 4894; bx += nb)
        prep_body(bx, tid, x, n_id, W, asrc, adst, xg, WT, wswd, dcnt, s2);
    grid.sync();

    for (int vb = blockIdx.x; vb < 500; vb += nb)
        escore_body(vb, tid, xg, wswd, es, ed);
    grid.sync();

    for (int vb = blockIdx.x; vb < 625; vb += nb)
        scatter_body(vb * 256 + tid, dst1, src1, dst2, src2, res1,
                     es, ed, dcnt, ew, srcp2);
    grid.sync();

    for (int vb = blockIdx.x; vb < MROWS / 4; vb += nb)
        agg1_body(vb, tid, xg, ew, dcnt, agg);
}

__global__ __launch_bounds__(256, 2) void k_coopB(
        const unsigned short* __restrict__ agg, const unsigned short* __restrict__ WT,
        const float* __restrict__ bias1, const float* __restrict__ W2,
        float* __restrict__ s2,
        const int* __restrict__ dcnt2, const int* __restrict__ srcp2,
        const int* __restrict__ res2, const float* __restrict__ asrc2,
        const float* __restrict__ adst2, const float* __restrict__ bias2,
        float* __restrict__ out)
{
    cg::grid_group grid = cg::this_grid();
    __shared__ unsigned short As[128 * 128];
    __shared__ unsigned short Bs[128 * 128];
    const int tid = threadIdx.x;

    for (int vb = blockIdx.x; vb < 125 * HEADS; vb += gridDim.x)
        out1_body(vb, tid, As, Bs, agg, WT, bias1, W2, s2);
    grid.sync();

    for (int vb = blockIdx.x; vb < (2 * ND2 + 255) / 256; vb += gridDim.x)
        agg2_body(vb * 256 + tid, s2, dcnt2, srcp2, res2, asrc2, adst2,
                  bias2, out);
}

// ===========================================================================
// Standalone fallback kernels (r15-proven path)
// ===========================================================================
__global__ __launch_bounds__(256) void k_prep(
        const float* __restrict__ x, const int* __restrict__ n_id,
        const float* __restrict__ W, const float* __restrict__ asrc,
        const float* __restrict__ adst,
        unsigned short* __restrict__ xg, unsigned short* __restrict__ WT,
        unsigned short* __restrict__ wswd,
        int* __restrict__ dcnt, float* __restrict__ s2)
{
    prep_body(blockIdx.x, threadIdx.x, x, n_id, W, asrc, adst, xg, WT, wswd,
              dcnt, s2);
}

__global__ __launch_bounds__(256) void k_escore(
        const unsigned short* __restrict__ xg,
        const unsigned short* __restrict__ wswd,
        float* __restrict__ es, float* __restrict__ ed)
{
    escore_body(blockIdx.x, threadIdx.x, xg, wswd, es, ed);
}

__global__ void k_scatter2(const int* __restrict__ dst1, const int* __restrict__ src1,
                           const int* __restrict__ dst2, const int* __restrict__ src2,
                           const int* __restrict__ res1,
                           const float* __restrict__ es, const float* __restrict__ ed,
                           int* __restrict__ dcnt, unsigned* __restrict__ ew,
                           int* __restrict__ srcp2)
{
    scatter_body(blockIdx.x * 256 + threadIdx.x, dst1, src1, dst2, src2, res1,
                 es, ed, dcnt, ew, srcp2);
}

__global__ __launch_bounds__(256) void k_agg1(
        const unsigned short* __restrict__ xg, const unsigned* __restrict__ ew,
        const int* __restrict__ dcnt, unsigned short* __restrict__ agg)
{
    agg1_body(blockIdx.x, threadIdx.x, xg, ew, dcnt, agg);
}

__global__ __launch_bounds__(256) void k_out1(
        const unsigned short* __restrict__ agg, const unsigned short* __restrict__ WT,
        const float* __restrict__ bias1, const float* __restrict__ W2,
        float* __restrict__ s2)
{
    __shared__ unsigned short As[128 * 128];
    __shared__ unsigned short Bs[128 * 128];
    // blockIdx maps to (row-tile, head): vb = h*125 + rowtile
    int vb = blockIdx.y * 125 + blockIdx.x;
    out1_body(vb, threadIdx.x, As, Bs, agg, WT, bias1, W2, s2);
}

__global__ void k_agg2(const float* __restrict__ s2, const int* __restrict__ dcnt2,
                       const int* __restrict__ srcp2, const int* __restrict__ res2,
                       const float* __restrict__ asrc, const float* __restrict__ adst,
                       const float* __restrict__ bias2, float* __restrict__ out)
{
    agg2_body(blockIdx.x * 256 + threadIdx.x, s2, dcnt2, srcp2, res2, asrc,
              adst, bias2, out);
}

// ===========================================================================
extern "C" void kernel_launch(void* const* d_in, const int* in_sizes, int n_in,
                              void* d_out, int out_size, void* d_ws, size_t ws_size,
                              hipStream_t stream)
{
    const float* x        = (const float*)d_in[0];
    const int* n_id1      = (const int*)d_in[1];
    const int* res_n_id1  = (const int*)d_in[2];
    const int* src1       = (const int*)d_in[3];
    const int* dst1       = (const int*)d_in[4];
    const int* res_n_id2  = (const int*)d_in[5];
    const int* src2       = (const int*)d_in[6];
    const int* dst2       = (const int*)d_in[7];
    const float* W1       = (const float*)d_in[8];
    const float* att_src1 = (const float*)d_in[9];
    const float* att_dst1 = (const float*)d_in[10];
    const float* bias1    = (const float*)d_in[11];
    const float* W2       = (const float*)d_in[12];
    const float* att_src2 = (const float*)d_in[13];
    const float* att_dst2 = (const float*)d_in[14];
    const float* bias2    = (const float*)d_in[15];

    // workspace layout (16B aligned), total ~95 MiB
    unsigned short* xg   = (unsigned short*)d_ws;
    unsigned short* W1T  = xg + (size_t)2 * NS1 * F_IN;
    unsigned short* wswd = W1T + (size_t)K1 * F_IN;
    unsigned short* agg  = wswd + (size_t)32 * F_IN;
    float* es  = (float*)(agg + (size_t)2 * ND1 * K1);
    float* ed  = es + (size_t)2 * NS1 * HEADS;
    float* s2  = ed + (size_t)2 * NS1 * HEADS;
    int* dcnt  = (int*)(s2 + (size_t)2 * ND1);
    int* srcp2 = dcnt + (ND1 + ND2);
    unsigned* ew = (unsigned*)(srcp2 + ND2 * CAP2 + 2);
    ew = (unsigned*)(((size_t)ew + 15) & ~(size_t)15);
    int* dcnt2 = dcnt + ND1;
    float* outp = (float*)d_out;

    // Runtime co-residency ground truth (host-side; free under graph replay)
    int nCU = 256;
    {
        hipDeviceProp_t prop;
        if (hipGetDeviceProperties(&prop, 0) == hipSuccess && prop.multiProcessorCount > 0)
            nCU = prop.multiProcessorCount;
    }
    int occA = 0, occB = 0;
    hipOccupancyMaxActiveBlocksPerMultiprocessor(&occA, (const void*)k_coopA, 256, 0);
    hipOccupancyMaxActiveBlocksPerMultiprocessor(&occB, (const void*)k_coopB, 256, 0);
    if (occA > 4) occA = 4;
    if (occB > 2) occB = 2;

    bool a_done = false, b_done = false;

    if (occA >= 1) {
        int gridA = occA * nCU;
        void* args[] = {
            (void*)&x, (void*)&n_id1, (void*)&W1, (void*)&att_src1, (void*)&att_dst1,
            (void*)&src1, (void*)&dst1, (void*)&src2, (void*)&dst2, (void*)&res_n_id1,
            (void*)&xg, (void*)&W1T, (void*)&wswd,
            (void*)&dcnt, (void*)&s2, (void*)&es, (void*)&ed,
            (void*)&ew, (void*)&srcp2, (void*)&agg
        };
        if (hipLaunchCooperativeKernel((const void*)k_coopA, dim3(gridA), dim3(256),
                                       args, 0, stream) == hipSuccess)
            a_done = true;
    }
    if (!a_done) {
        k_prep<<<4894, 256, 0, stream>>>(x, n_id1, W1, att_src1, att_dst1,
                                         xg, W1T, wswd, dcnt, s2);
        k_escore<<<500, 256, 0, stream>>>(xg, wswd, es, ed);
        k_scatter2<<<(E1 + E2 + 255) / 256, 256, 0, stream>>>(
            dst1, src1, dst2, src2, res_n_id1, es, ed, dcnt, ew, srcp2);
        k_agg1<<<MROWS / 4, 256, 0, stream>>>(xg, ew, dcnt, agg);
    }

    if (occB >= 1) {
        int gridB = occB * nCU;
        void* args[] = {
            (void*)&agg, (void*)&W1T, (void*)&bias1, (void*)&W2,
            (void*)&s2, (void*)&dcnt2, (void*)&srcp2, (void*)&res_n_id2,
            (void*)&att_src2, (void*)&att_dst2, (void*)&bias2, (void*)&outp
        };
        if (hipLaunchCooperativeKernel((const void*)k_coopB, dim3(gridB), dim3(256),
                                       args, 0, stream) == hipSuccess)
            b_done = true;
    }
    if (!b_done) {
        k_out1<<<dim3(125, HEADS), 256, 0, stream>>>(agg, W1T, bias1, W2, s2);
        k_agg2<<<(2 * ND2 + 255) / 256, 256, 0, stream>>>(
            s2, dcnt2, srcp2, res_n_id2, att_src2, att_dst2, bias2, outp);
    }
}

// Round 19
// 101.351 us; speedup vs baseline: 3.6496x; 3.6496x over previous
//
#include <hip/hip_runtime.h>
#include <hip/hip_bf16.h>

// Sizes fixed by the problem
#define B2      2
#define NX      20000
#define F_IN    128
#define NS1     16000
#define ND1     8000
#define E1      100000
#define ND2     4000
#define E2      60000
#define HEADS   12
#define CH      128
#define K1      1536   // HEADS*CH
#define MROWS   (2*ND1) // 16000
#define CAP1    64     // bucket capacity graph1
#define CAP2    64     // bucket capacity graph2

typedef __bf16 bf16x8 __attribute__((ext_vector_type(8)));
typedef float  f32x4  __attribute__((ext_vector_type(4)));

static __device__ __forceinline__ float lrelu(float x) { return x > 0.f ? x : 0.2f * x; }

static __device__ __forceinline__ unsigned short f2bf(float f) {
    union { float f; unsigned u; } v; v.f = f;
    unsigned r = v.u + 0x7fffu + ((v.u >> 16) & 1u);
    return (unsigned short)(r >> 16);
}

// async global->LDS, 16 bytes per lane
static __device__ __forceinline__ void gld16(const void* g, void* l) {
    __builtin_amdgcn_global_load_lds(
        (const __attribute__((address_space(1))) unsigned int*)g,
        (__attribute__((address_space(3))) unsigned int*)l, 16, 0, 0);
}

// ---------------------------------------------------------------------------
// Fused prep: [0,4000) convA | [4000,4768) convB | [4768,4784) ws
//             | [4784,4894) zero dcnt(12000 ints) + s2(16000 f32)
// ---------------------------------------------------------------------------
__global__ __launch_bounds__(256) void k_prep(const float* __restrict__ x,
                                              const int* __restrict__ n_id,
                                              const float* __restrict__ W,
                                              const float* __restrict__ asrc,
                                              const float* __restrict__ adst,
                                              unsigned short* __restrict__ xg,
                                              unsigned short* __restrict__ WT,
                                              unsigned short* __restrict__ wswd,
                                              int* __restrict__ dcnt,
                                              float* __restrict__ s2)
{
    const int bx = blockIdx.x;
    const int tid = threadIdx.x;
    if (bx < 4000) {
        int t = bx * 256 + tid;                      // float4 units
        int row = t >> 5;
        int c4 = (t & 31) << 2;
        int b = row >= NS1 ? 1 : 0;
        int node = n_id[row - b * NS1];
        const float4 v = *reinterpret_cast<const float4*>(
            x + ((size_t)(b * NX + node)) * F_IN + c4);
        ushort4 o;
        o.x = f2bf(v.x); o.y = f2bf(v.y); o.z = f2bf(v.z); o.w = f2bf(v.w);
        *reinterpret_cast<ushort4*>(xg + (size_t)row * F_IN + c4) = o;
    } else if (bx < 4768) {
        int t = (bx - 4000) * 256 + tid;             // 0..196607
        int k = t / K1;
        int n = t - k * K1;
        WT[(size_t)n * F_IN + k] = f2bf(W[t]);
    } else if (bx < 4784) {
        int t = (bx - 4768) * 256 + tid;             // 0..4095
        int n = t >> 7;
        int c = t & 127;
        float acc = 0.f;
        if (n < 24) {
            int h = n < 12 ? n : n - 12;
            const float* att = (n < 12 ? asrc : adst) + h * CH;
            const float* wr = W + (size_t)c * K1 + h * CH;
            for (int j = 0; j < CH; ++j) acc += wr[j] * att[j];
        }
        wswd[(size_t)n * F_IN + c] = f2bf(acc);
    } else {
        int t = (bx - 4784) * 256 + tid;
        if (t < ND1 + ND2) dcnt[t] = 0;
        else if (t < ND1 + ND2 + MROWS) s2[t - (ND1 + ND2)] = 0.f;
    }
}

// ---------------------------------------------------------------------------
// Scores: [32000,128] @ wswd^T -> es[row][12], ed[row][12].  MFMA.
// ---------------------------------------------------------------------------
__global__ __launch_bounds__(256) void k_escore(const unsigned short* __restrict__ xg,
                                                const unsigned short* __restrict__ wswd,
                                                float* __restrict__ es,
                                                float* __restrict__ ed)
{
    const int tid = threadIdx.x;
    const int wave = tid >> 6, lane = tid & 63;
    const int l15 = lane & 15, l4 = lane >> 4;
    const int rt = blockIdx.x * 4 + wave;            // 0..1999
    const int row0 = rt * 16;
    const unsigned short* Ap = xg + (size_t)(row0 + l15) * F_IN + l4 * 8;

    f32x4 acc[2] = {f32x4{0,0,0,0}, f32x4{0,0,0,0}};
#pragma unroll
    for (int kk = 0; kk < 4; ++kk) {
        bf16x8 a = *reinterpret_cast<const bf16x8*>(Ap + kk * 32);
#pragma unroll
        for (int c = 0; c < 2; ++c) {
            bf16x8 b = *reinterpret_cast<const bf16x8*>(
                wswd + (size_t)(c * 16 + l15) * F_IN + kk * 32 + l4 * 8);
            acc[c] = __builtin_amdgcn_mfma_f32_16x16x32_bf16(a, b, acc[c], 0, 0, 0);
        }
    }
#pragma unroll
    for (int c = 0; c < 2; ++c) {
        int col = c * 16 + l15;
#pragma unroll
        for (int r = 0; r < 4; ++r) {
            int row = row0 + l4 * 4 + r;
            float v = acc[c][r];
            if (col < 12)       es[(size_t)row * HEADS + col] = v;
            else if (col < 24)  ed[(size_t)row * HEADS + (col - 12)] = v;
        }
    }
}

// ---------------------------------------------------------------------------
// Bucket scatter + per-edge softmax weights (both graphs). No CSR scan:
// slot k = atomicAdd(dcnt[d],1); bucket base d*CAP.
// Graph1: ew[b][d][k] = 32B record {se, w0..w5 packed bf16, pad}.
// Graph2: srcp2[d*CAP2+k] = src node.
// ---------------------------------------------------------------------------
__global__ void k_scatter2(const int* __restrict__ dst1, const int* __restrict__ src1,
                           const int* __restrict__ dst2, const int* __restrict__ src2,
                           const int* __restrict__ res1,
                           const float* __restrict__ es, const float* __restrict__ ed,
                           int* __restrict__ dcnt, unsigned* __restrict__ ew,
                           int* __restrict__ srcp2)
{
    int e = blockIdx.x * 256 + threadIdx.x;
    if (e < E1) {
        int d = dst1[e];
        int k = atomicAdd(&dcnt[d], 1);
        if (k < CAP1) {
            int s = src1[e];
            int rd = res1[d];
#pragma unroll
            for (int b = 0; b < 2; ++b) {
                const float* esp = es + ((size_t)(b * NS1 + s)) * HEADS;
                const float* edp = ed + ((size_t)(b * NS1 + rd)) * HEADS;
                unsigned w[6];
#pragma unroll
                for (int j = 0; j < 6; ++j) {
                    float w0 = __expf(lrelu(esp[2 * j] + edp[2 * j]));
                    float w1 = __expf(lrelu(esp[2 * j + 1] + edp[2 * j + 1]));
                    w[j] = (unsigned)f2bf(w0) | ((unsigned)f2bf(w1) << 16);
                }
                unsigned* rp = ew + ((size_t)b * ND1 * CAP1 + (size_t)d * CAP1 + k) * 8;
                *reinterpret_cast<uint4*>(rp) = make_uint4((unsigned)s, w[0], w[1], w[2]);
                *reinterpret_cast<uint4*>(rp + 4) = make_uint4(w[3], w[4], w[5], 0u);
            }
        }
    } else if (e < E1 + E2) {
        int ee = e - E1;
        int d = dst2[ee];
        int k = atomicAdd(&dcnt[ND1 + d], 1);
        if (k < CAP2) srcp2[d * CAP2 + k] = src2[ee];
    }
}

// ---------------------------------------------------------------------------
// Layer-1 aggregate in F space, v10: r15's proven scalar body + manual
// software pipeline. Edge p+1's 32B record is prefetched while edge p
// computes, so the dependent chain per iteration is only record(reg)->xg.
// One wave per (dst,b) task; zero LDS, zero barriers.
// ---------------------------------------------------------------------------
__global__ __launch_bounds__(256) void k_agg1(const unsigned short* __restrict__ xg,
                                              const unsigned* __restrict__ ew,
                                              const int* __restrict__ dcnt,
                                              unsigned short* __restrict__ agg)
{
    const int tid = threadIdx.x;
    const int wv = tid >> 6, lane = tid & 63;
    const int task = blockIdx.x * 4 + wv;        // 0..16000
    const int b = task >= ND1 ? 1 : 0;           // batch
    const int i = task - b * ND1;                // dst node
    const int c2 = lane * 2;

    const int deg = min(dcnt[i], CAP1);
    const uint4* eb = reinterpret_cast<const uint4*>(
        ew + ((size_t)b * ND1 * CAP1 + (size_t)i * CAP1) * 8);
    const unsigned short* xb = xg + (size_t)b * NS1 * F_IN + c2;

    float acc[24];
    float den[12];
#pragma unroll
    for (int r = 0; r < 24; ++r) acc[r] = 0.f;
#pragma unroll
    for (int h = 0; h < 12; ++h) den[h] = 0.f;

    if (deg > 0) {
        uint4 r0 = eb[0];
        uint4 r1 = eb[1];
        for (int p = 0; p < deg; ++p) {
            // issue xg load immediately (record already in registers)
            int se = (int)r0.x;
            unsigned xv = *reinterpret_cast<const unsigned*>(xb + (size_t)se * F_IN);
            // prefetch next record (clamped; overlaps with compute below)
            int pn = p + 1 < deg ? p + 1 : deg - 1;
            uint4 n0 = eb[2 * pn];
            uint4 n1 = eb[2 * pn + 1];

            float x0 = __uint_as_float(xv << 16);
            float x1 = __uint_as_float(xv & 0xffff0000u);
            unsigned wd[6] = {r0.y, r0.z, r0.w, r1.x, r1.y, r1.z};
#pragma unroll
            for (int j = 0; j < 6; ++j) {
                unsigned d = wd[j];
                float w0 = __uint_as_float(d << 16);
                float w1 = __uint_as_float(d & 0xffff0000u);
                acc[4 * j + 0] += w0 * x0; acc[4 * j + 1] += w0 * x1;
                acc[4 * j + 2] += w1 * x0; acc[4 * j + 3] += w1 * x1;
                den[2 * j]     += w0;      den[2 * j + 1] += w1;
            }
            r0 = n0;
            r1 = n1;
        }
    }

    // finalize: den complete per-lane (lane-uniform); normalize, pack, write
    const size_t rowbase = ((size_t)(b * ND1 + i)) * K1;
#pragma unroll
    for (int j = 0; j < 12; ++j) {
        float r = 1.f / (den[j] + 1e-16f);
        unsigned pk = (unsigned)f2bf(acc[2 * j] * r) |
                      ((unsigned)f2bf(acc[2 * j + 1] * r) << 16);
        *reinterpret_cast<unsigned*>(agg + rowbase + j * CH + c2) = pk;
    }
}

// ---------------------------------------------------------------------------
// Post-aggregation projection: LDS-staged MFMA GEMM, 128 rows x 1 head per
// block; epilogue bias+relu+dot(W2) atomically accumulated into s2[row].
// ---------------------------------------------------------------------------
__global__ __launch_bounds__(256) void k_out1(const unsigned short* __restrict__ agg,
                                              const unsigned short* __restrict__ WT,
                                              const float* __restrict__ bias1,
                                              const float* __restrict__ W2,
                                              float* __restrict__ s2)
{
    __shared__ unsigned short As[128 * 128];   // [row][k] chunk-swizzled
    __shared__ unsigned short Bs[128 * 128];   // [n][k]  chunk-swizzled

    const int tid = threadIdx.x;
    const int wv = tid >> 6, lane = tid & 63;
    const int l15 = lane & 15, l4 = lane >> 4;
    const int row0 = blockIdx.x * 128;
    const int h = blockIdx.y;

    {
        const unsigned short* ga = agg + (size_t)row0 * K1 + h * CH;
        const unsigned short* gb = WT + (size_t)(h * CH) * F_IN;
#pragma unroll
        for (int p = 0; p < 8; ++p) {
            int r = p * 16 + wv * 4 + l4;            // LDS row this lane feeds
            int cs = l15 ^ (r & 7);                  // pre-swizzled source chunk
            gld16(ga + (size_t)r * K1 + cs * 8, As + (p * 16 + wv * 4) * 128);
            gld16(gb + (size_t)r * F_IN + cs * 8, Bs + (p * 16 + wv * 4) * 128);
        }
    }
    __syncthreads();   // compiler drains vmcnt(0) before barrier

    f32x4 acc[2][8];
#pragma unroll
    for (int m = 0; m < 2; ++m)
#pragma unroll
        for (int c = 0; c < 8; ++c) acc[m][c] = f32x4{0, 0, 0, 0};

#pragma unroll
    for (int kk = 0; kk < 4; ++kk) {
        bf16x8 a[2];
#pragma unroll
        for (int m = 0; m < 2; ++m) {
            int r = wv * 32 + m * 16 + l15;
            int ch = (l4 + kk * 4) ^ (r & 7);
            a[m] = *reinterpret_cast<const bf16x8*>(As + r * 128 + ch * 8);
        }
#pragma unroll
        for (int c = 0; c < 8; ++c) {
            int n = c * 16 + l15;
            int ch = (l4 + kk * 4) ^ (n & 7);
            bf16x8 bb = *reinterpret_cast<const bf16x8*>(Bs + n * 128 + ch * 8);
#pragma unroll
            for (int m = 0; m < 2; ++m)
                acc[m][c] = __builtin_amdgcn_mfma_f32_16x16x32_bf16(a[m], bb,
                                                                    acc[m][c], 0, 0, 0);
        }
    }

#pragma unroll
    for (int m = 0; m < 2; ++m) {
        float part[4] = {0.f, 0.f, 0.f, 0.f};
#pragma unroll
        for (int c = 0; c < 8; ++c) {
            int n = h * CH + c * 16 + l15;
            float bi = bias1[n];
            float w2 = W2[n];
#pragma unroll
            for (int r = 0; r < 4; ++r) {
                float v = acc[m][c][r] + bi;
                v = v > 0.f ? v : 0.f;
                part[r] += v * w2;
            }
        }
#pragma unroll
        for (int r = 0; r < 4; ++r) {
#pragma unroll
            for (int o = 1; o < 16; o <<= 1) part[r] += __shfl_xor(part[r], o);
        }
        if (l15 == 0) {
            int row = row0 + wv * 32 + m * 16 + l4 * 4;
#pragma unroll
            for (int r = 0; r < 4; ++r)
                atomicAdd(&s2[row + r], part[r]);
        }
    }
}

// ---------------------------------------------------------------------------
// Layer-2 (heads=1, ch=1), bucket-indexed: one thread per (dst j, batch b).
// ---------------------------------------------------------------------------
__global__ void k_agg2(const float* __restrict__ s2,
                       const int* __restrict__ dcnt2,
                       const int* __restrict__ srcp2,
                       const int* __restrict__ res2,
                       const float* __restrict__ asrc,
                       const float* __restrict__ adst,
                       const float* __restrict__ bias2,
                       float* __restrict__ out)
{
    int t = blockIdx.x * 256 + threadIdx.x;
    if (t >= 2 * ND2) return;
    int b = t / ND2, j = t - b * ND2;
    float a_s = asrc[0], a_d = adst[0];
    float edl = s2[(size_t)b * ND1 + res2[j]] * a_d;
    int deg = min(dcnt2[j], CAP2);
    float den = 0.f, num = 0.f;
    for (int k = 0; k < deg; ++k) {
        int s = srcp2[j * CAP2 + k];
        float v = s2[b * ND1 + s];
        float w = __expf(lrelu(v * a_s + edl));
        den += w;
        num += w * v;
    }
    float o = (deg > 0) ? num / (den + 1e-16f) : 0.f;
    out[(size_t)b * ND2 + j] = o + bias2[0];
}

// ---------------------------------------------------------------------------
extern "C" void kernel_launch(void* const* d_in, const int* in_sizes, int n_in,
                              void* d_out, int out_size, void* d_ws, size_t ws_size,
                              hipStream_t stream)
{
    const float* x        = (const float*)d_in[0];
    const int* n_id1      = (const int*)d_in[1];
    const int* res_n_id1  = (const int*)d_in[2];
    const int* src1       = (const int*)d_in[3];
    const int* dst1       = (const int*)d_in[4];
    const int* res_n_id2  = (const int*)d_in[5];
    const int* src2       = (const int*)d_in[6];
    const int* dst2       = (const int*)d_in[7];
    const float* W1       = (const float*)d_in[8];
    const float* att_src1 = (const float*)d_in[9];
    const float* att_dst1 = (const float*)d_in[10];
    const float* bias1    = (const float*)d_in[11];
    const float* W2       = (const float*)d_in[12];
    const float* att_src2 = (const float*)d_in[13];
    const float* att_dst2 = (const float*)d_in[14];
    const float* bias2    = (const float*)d_in[15];

    // workspace layout (16B aligned), total ~95 MiB
    unsigned short* xg   = (unsigned short*)d_ws;            // 4,096,000 ush
    unsigned short* W1T  = xg + (size_t)2 * NS1 * F_IN;      //   196,608
    unsigned short* wswd = W1T + (size_t)K1 * F_IN;          //     4,096
    unsigned short* agg  = wswd + (size_t)32 * F_IN;         // 24,576,000
    float* es  = (float*)(agg + (size_t)2 * ND1 * K1);       //   384,000 f32
    float* ed  = es + (size_t)2 * NS1 * HEADS;               //   384,000
    float* s2  = ed + (size_t)2 * NS1 * HEADS;               //    16,000
    int* dcnt  = (int*)(s2 + (size_t)2 * ND1);               // 12,000 (g1|g2)
    int* srcp2 = dcnt + (ND1 + ND2);                         // 256,000 (g2)
    unsigned* ew = (unsigned*)(srcp2 + ND2 * CAP2 + 2);      // 8,192,000 u32
    ew = (unsigned*)(((size_t)ew + 15) & ~(size_t)15);       // 16B align

    // 1) fused prep (convA + convB + ws + zero dcnt/s2)
    k_prep<<<4894, 256, 0, stream>>>(x, n_id1, W1, att_src1, att_dst1,
                                     xg, W1T, wswd, dcnt, s2);

    // 2) scores (MFMA)
    k_escore<<<500, 256, 0, stream>>>(xg, wswd, es, ed);

    // 3) bucket scatter + per-edge weights (count fused via atomic slot)
    k_scatter2<<<(E1 + E2 + 255) / 256, 256, 0, stream>>>(
        dst1, src1, dst2, src2, res_n_id1, es, ed, dcnt, ew, srcp2);

    // 4) layer-1 aggregate in F space (one wave per (dst,b) task, pipelined)
    k_agg1<<<MROWS / 4, 256, 0, stream>>>(xg, ew, dcnt, agg);

    // 5) projection + bias + relu + dot(W2), atomically into s2
    k_out1<<<dim3(MROWS / 128, HEADS), 256, 0, stream>>>(agg, W1T, bias1, W2, s2);

    // 6) layer-2
    k_agg2<<<(2 * ND2 + 255) / 256, 256, 0, stream>>>(s2, dcnt + ND1, srcp2,
                                                      res_n_id2, att_src2,
                                                      att_dst2, bias2,
                                                      (float*)d_out);
}

// Round 20
// 98.079 us; speedup vs baseline: 3.7713x; 1.0334x over previous
//
#include <hip/hip_runtime.h>
#include <hip/hip_bf16.h>

// Sizes fixed by the problem
#define B2      2
#define NX      20000
#define F_IN    128
#define NS1     16000
#define ND1     8000
#define E1      100000
#define ND2     4000
#define E2      60000
#define HEADS   12
#define CH      128
#define K1      1536   // HEADS*CH
#define MROWS   (2*ND1) // 16000
#define CAP1    64     // bucket capacity graph1 (max deg ~28, Poisson-safe)
#define CAP2    64     // bucket capacity graph2 (max deg ~33)

typedef __bf16 bf16x8 __attribute__((ext_vector_type(8)));
typedef float  f32x4  __attribute__((ext_vector_type(4)));

static __device__ __forceinline__ float lrelu(float x) { return x > 0.f ? x : 0.2f * x; }

static __device__ __forceinline__ unsigned short f2bf(float f) {
    union { float f; unsigned u; } v; v.f = f;
    unsigned r = v.u + 0x7fffu + ((v.u >> 16) & 1u);
    return (unsigned short)(r >> 16);
}

// async global->LDS, 16 bytes per lane; LDS dest is wave-uniform base + lane*16
static __device__ __forceinline__ void gld16(const void* g, void* l) {
    __builtin_amdgcn_global_load_lds(
        (const __attribute__((address_space(1))) unsigned int*)g,
        (__attribute__((address_space(3))) unsigned int*)l, 16, 0, 0);
}

// ---------------------------------------------------------------------------
// Fused prep: [0,4000) convA | [4000,4768) convB | [4768,4784) ws
//             | [4784,4894) zero dcnt(12000 ints) + s2(16000 f32)
// ---------------------------------------------------------------------------
__global__ __launch_bounds__(256) void k_prep(const float* __restrict__ x,
                                              const int* __restrict__ n_id,
                                              const float* __restrict__ W,
                                              const float* __restrict__ asrc,
                                              const float* __restrict__ adst,
                                              unsigned short* __restrict__ xg,
                                              unsigned short* __restrict__ WT,
                                              unsigned short* __restrict__ wswd,
                                              int* __restrict__ dcnt,
                                              float* __restrict__ s2)
{
    const int bx = blockIdx.x;
    const int tid = threadIdx.x;
    if (bx < 4000) {
        int t = bx * 256 + tid;                      // float4 units
        int row = t >> 5;
        int c4 = (t & 31) << 2;
        int b = row >= NS1 ? 1 : 0;
        int node = n_id[row - b * NS1];
        const float4 v = *reinterpret_cast<const float4*>(
            x + ((size_t)(b * NX + node)) * F_IN + c4);
        ushort4 o;
        o.x = f2bf(v.x); o.y = f2bf(v.y); o.z = f2bf(v.z); o.w = f2bf(v.w);
        *reinterpret_cast<ushort4*>(xg + (size_t)row * F_IN + c4) = o;
    } else if (bx < 4768) {
        int t = (bx - 4000) * 256 + tid;             // 0..196607
        int k = t / K1;
        int n = t - k * K1;
        WT[(size_t)n * F_IN + k] = f2bf(W[t]);
    } else if (bx < 4784) {
        int t = (bx - 4768) * 256 + tid;             // 0..4095
        int n = t >> 7;
        int c = t & 127;
        float acc = 0.f;
        if (n < 24) {
            int h = n < 12 ? n : n - 12;
            const float* att = (n < 12 ? asrc : adst) + h * CH;
            const float* wr = W + (size_t)c * K1 + h * CH;
            for (int j = 0; j < CH; ++j) acc += wr[j] * att[j];
        }
        wswd[(size_t)n * F_IN + c] = f2bf(acc);
    } else {
        int t = (bx - 4784) * 256 + tid;
        if (t < ND1 + ND2) dcnt[t] = 0;
        else if (t < ND1 + ND2 + MROWS) s2[t - (ND1 + ND2)] = 0.f;
    }
}

// ---------------------------------------------------------------------------
// Scores: [32000,128] @ wswd^T -> es[row][12], ed[row][12].  MFMA.
// ---------------------------------------------------------------------------
__global__ __launch_bounds__(256) void k_escore(const unsigned short* __restrict__ xg,
                                                const unsigned short* __restrict__ wswd,
                                                float* __restrict__ es,
                                                float* __restrict__ ed)
{
    const int tid = threadIdx.x;
    const int wave = tid >> 6, lane = tid & 63;
    const int l15 = lane & 15, l4 = lane >> 4;
    const int rt = blockIdx.x * 4 + wave;            // 0..1999
    const int row0 = rt * 16;
    const unsigned short* Ap = xg + (size_t)(row0 + l15) * F_IN + l4 * 8;

    f32x4 acc[2] = {f32x4{0,0,0,0}, f32x4{0,0,0,0}};
#pragma unroll
    for (int kk = 0; kk < 4; ++kk) {
        bf16x8 a = *reinterpret_cast<const bf16x8*>(Ap + kk * 32);
#pragma unroll
        for (int c = 0; c < 2; ++c) {
            bf16x8 b = *reinterpret_cast<const bf16x8*>(
                wswd + (size_t)(c * 16 + l15) * F_IN + kk * 32 + l4 * 8);
            acc[c] = __builtin_amdgcn_mfma_f32_16x16x32_bf16(a, b, acc[c], 0, 0, 0);
        }
    }
#pragma unroll
    for (int c = 0; c < 2; ++c) {
        int col = c * 16 + l15;
#pragma unroll
        for (int r = 0; r < 4; ++r) {
            int row = row0 + l4 * 4 + r;
            float v = acc[c][r];
            if (col < 12)       es[(size_t)row * HEADS + col] = v;
            else if (col < 24)  ed[(size_t)row * HEADS + (col - 12)] = v;
        }
    }
}

// ---------------------------------------------------------------------------
// Bucket scatter + per-edge softmax weights (both graphs). No CSR scan:
// slot k = atomicAdd(dcnt[d],1); bucket base d*CAP.
// Graph1: ew[b][d][k] = 32B record {se, w0..w5 packed bf16, pad}.
// Graph2: srcp2[d*CAP2+k] = src node.
// ---------------------------------------------------------------------------
__global__ void k_scatter2(const int* __restrict__ dst1, const int* __restrict__ src1,
                           const int* __restrict__ dst2, const int* __restrict__ src2,
                           const int* __restrict__ res1,
                           const float* __restrict__ es, const float* __restrict__ ed,
                           int* __restrict__ dcnt, unsigned* __restrict__ ew,
                           int* __restrict__ srcp2)
{
    int e = blockIdx.x * 256 + threadIdx.x;
    if (e < E1) {
        int d = dst1[e];
        int k = atomicAdd(&dcnt[d], 1);
        if (k < CAP1) {
            int s = src1[e];
            int rd = res1[d];
#pragma unroll
            for (int b = 0; b < 2; ++b) {
                const float* esp = es + ((size_t)(b * NS1 + s)) * HEADS;
                const float* edp = ed + ((size_t)(b * NS1 + rd)) * HEADS;
                unsigned w[6];
#pragma unroll
                for (int j = 0; j < 6; ++j) {
                    float w0 = __expf(lrelu(esp[2 * j] + edp[2 * j]));
                    float w1 = __expf(lrelu(esp[2 * j + 1] + edp[2 * j + 1]));
                    w[j] = (unsigned)f2bf(w0) | ((unsigned)f2bf(w1) << 16);
                }
                unsigned* rp = ew + ((size_t)b * ND1 * CAP1 + (size_t)d * CAP1 + k) * 8;
                *reinterpret_cast<uint4*>(rp) = make_uint4((unsigned)s, w[0], w[1], w[2]);
                *reinterpret_cast<uint4*>(rp + 4) = make_uint4(w[3], w[4], w[5], 0u);
            }
        }
    } else if (e < E1 + E2) {
        int ee = e - E1;
        int d = dst2[ee];
        int k = atomicAdd(&dcnt[ND1 + d], 1);
        if (k < CAP2) srcp2[d * CAP2 + k] = src2[ee];
    }
}

// ---------------------------------------------------------------------------
// Layer-1 aggregate in F space (r15-proven v7 body, bucket-indexed):
// ONE WAVE per (dst,b) task; per edge 2 broadcast uint4 + 1 coalesced xg
// dword, 24 FMA + 12 den adds. Zero LDS, zero barriers. The #pragma unroll 2
// lets the compiler dual-issue the record/xg loads across iterations.
// ---------------------------------------------------------------------------
__global__ __launch_bounds__(256) void k_agg1(const unsigned short* __restrict__ xg,
                                              const unsigned* __restrict__ ew,
                                              const int* __restrict__ dcnt,
                                              unsigned short* __restrict__ agg)
{
    const int tid = threadIdx.x;
    const int wv = tid >> 6, lane = tid & 63;
    const int task = blockIdx.x * 4 + wv;        // 0..16000
    const int b = task >= ND1 ? 1 : 0;           // batch
    const int i = task - b * ND1;                // dst node
    const int c2 = lane * 2;

    const int deg = min(dcnt[i], CAP1);
    const uint4* eb = reinterpret_cast<const uint4*>(
        ew + ((size_t)b * ND1 * CAP1 + (size_t)i * CAP1) * 8);
    const unsigned short* xb = xg + (size_t)b * NS1 * F_IN + c2;

    float acc[24];
    float den[12];
#pragma unroll
    for (int r = 0; r < 24; ++r) acc[r] = 0.f;
#pragma unroll
    for (int h = 0; h < 12; ++h) den[h] = 0.f;

#pragma unroll 2
    for (int p = 0; p < deg; ++p) {
        uint4 r0 = eb[2 * p];
        uint4 r1 = eb[2 * p + 1];
        int se = (int)r0.x;
        unsigned xv = *reinterpret_cast<const unsigned*>(xb + (size_t)se * F_IN);
        float x0 = __uint_as_float(xv << 16);
        float x1 = __uint_as_float(xv & 0xffff0000u);
        unsigned wd[6] = {r0.y, r0.z, r0.w, r1.x, r1.y, r1.z};
#pragma unroll
        for (int j = 0; j < 6; ++j) {
            unsigned d = wd[j];
            float w0 = __uint_as_float(d << 16);
            float w1 = __uint_as_float(d & 0xffff0000u);
            acc[4 * j + 0] += w0 * x0; acc[4 * j + 1] += w0 * x1;
            acc[4 * j + 2] += w1 * x0; acc[4 * j + 3] += w1 * x1;
            den[2 * j]     += w0;      den[2 * j + 1] += w1;
        }
    }

    // finalize: den complete per-lane (lane-uniform); normalize, pack, write
    const size_t rowbase = ((size_t)(b * ND1 + i)) * K1;
#pragma unroll
    for (int j = 0; j < 12; ++j) {
        float r = 1.f / (den[j] + 1e-16f);
        unsigned pk = (unsigned)f2bf(acc[2 * j] * r) |
                      ((unsigned)f2bf(acc[2 * j + 1] * r) << 16);
        *reinterpret_cast<unsigned*>(agg + rowbase + j * CH + c2) = pk;
    }
}

// ---------------------------------------------------------------------------
// Post-aggregation projection: LDS-staged MFMA GEMM, 128 rows x 1 head per
// block; epilogue bias+relu+dot(W2) atomically accumulated into s2[row].
// ---------------------------------------------------------------------------
__global__ __launch_bounds__(256) void k_out1(const unsigned short* __restrict__ agg,
                                              const unsigned short* __restrict__ WT,
                                              const float* __restrict__ bias1,
                                              const float* __restrict__ W2,
                                              float* __restrict__ s2)
{
    __shared__ unsigned short As[128 * 128];   // [row][k] chunk-swizzled
    __shared__ unsigned short Bs[128 * 128];   // [n][k]  chunk-swizzled

    const int tid = threadIdx.x;
    const int wv = tid >> 6, lane = tid & 63;
    const int l15 = lane & 15, l4 = lane >> 4;
    const int row0 = blockIdx.x * 128;
    const int h = blockIdx.y;

    {
        const unsigned short* ga = agg + (size_t)row0 * K1 + h * CH;
        const unsigned short* gb = WT + (size_t)(h * CH) * F_IN;
#pragma unroll
        for (int p = 0; p < 8; ++p) {
            int r = p * 16 + wv * 4 + l4;            // LDS row this lane feeds
            int cs = l15 ^ (r & 7);                  // pre-swizzled source chunk
            gld16(ga + (size_t)r * K1 + cs * 8, As + (p * 16 + wv * 4) * 128);
            gld16(gb + (size_t)r * F_IN + cs * 8, Bs + (p * 16 + wv * 4) * 128);
        }
    }
    __syncthreads();   // compiler drains vmcnt(0) before barrier

    f32x4 acc[2][8];
#pragma unroll
    for (int m = 0; m < 2; ++m)
#pragma unroll
        for (int c = 0; c < 8; ++c) acc[m][c] = f32x4{0, 0, 0, 0};

#pragma unroll
    for (int kk = 0; kk < 4; ++kk) {
        bf16x8 a[2];
#pragma unroll
        for (int m = 0; m < 2; ++m) {
            int r = wv * 32 + m * 16 + l15;
            int ch = (l4 + kk * 4) ^ (r & 7);
            a[m] = *reinterpret_cast<const bf16x8*>(As + r * 128 + ch * 8);
        }
#pragma unroll
        for (int c = 0; c < 8; ++c) {
            int n = c * 16 + l15;
            int ch = (l4 + kk * 4) ^ (n & 7);
            bf16x8 bb = *reinterpret_cast<const bf16x8*>(Bs + n * 128 + ch * 8);
#pragma unroll
            for (int m = 0; m < 2; ++m)
                acc[m][c] = __builtin_amdgcn_mfma_f32_16x16x32_bf16(a[m], bb,
                                                                    acc[m][c], 0, 0, 0);
        }
    }

#pragma unroll
    for (int m = 0; m < 2; ++m) {
        float part[4] = {0.f, 0.f, 0.f, 0.f};
#pragma unroll
        for (int c = 0; c < 8; ++c) {
            int n = h * CH + c * 16 + l15;
            float bi = bias1[n];
            float w2 = W2[n];
#pragma unroll
            for (int r = 0; r < 4; ++r) {
                float v = acc[m][c][r] + bi;
                v = v > 0.f ? v : 0.f;
                part[r] += v * w2;
            }
        }
#pragma unroll
        for (int r = 0; r < 4; ++r) {
#pragma unroll
            for (int o = 1; o < 16; o <<= 1) part[r] += __shfl_xor(part[r], o);
        }
        if (l15 == 0) {
            int row = row0 + wv * 32 + m * 16 + l4 * 4;
#pragma unroll
            for (int r = 0; r < 4; ++r)
                atomicAdd(&s2[row + r], part[r]);
        }
    }
}

// ---------------------------------------------------------------------------
// Layer-2 (heads=1, ch=1), bucket-indexed: one thread per (dst j, batch b).
// ---------------------------------------------------------------------------
__global__ void k_agg2(const float* __restrict__ s2,
                       const int* __restrict__ dcnt2,
                       const int* __restrict__ srcp2,
                       const int* __restrict__ res2,
                       const float* __restrict__ asrc,
                       const float* __restrict__ adst,
                       const float* __restrict__ bias2,
                       float* __restrict__ out)
{
    int t = blockIdx.x * 256 + threadIdx.x;
    if (t >= 2 * ND2) return;
    int b = t / ND2, j = t - b * ND2;
    float a_s = asrc[0], a_d = adst[0];
    float edl = s2[(size_t)b * ND1 + res2[j]] * a_d;
    int deg = min(dcnt2[j], CAP2);
    float den = 0.f, num = 0.f;
    for (int k = 0; k < deg; ++k) {
        int s = srcp2[j * CAP2 + k];
        float v = s2[b * ND1 + s];
        float w = __expf(lrelu(v * a_s + edl));
        den += w;
        num += w * v;
    }
    float o = (deg > 0) ? num / (den + 1e-16f) : 0.f;
    out[(size_t)b * ND2 + j] = o + bias2[0];
}

// ---------------------------------------------------------------------------
extern "C" void kernel_launch(void* const* d_in, const int* in_sizes, int n_in,
                              void* d_out, int out_size, void* d_ws, size_t ws_size,
                              hipStream_t stream)
{
    const float* x        = (const float*)d_in[0];
    const int* n_id1      = (const int*)d_in[1];
    const int* res_n_id1  = (const int*)d_in[2];
    const int* src1       = (const int*)d_in[3];
    const int* dst1       = (const int*)d_in[4];
    const int* res_n_id2  = (const int*)d_in[5];
    const int* src2       = (const int*)d_in[6];
    const int* dst2       = (const int*)d_in[7];
    const float* W1       = (const float*)d_in[8];
    const float* att_src1 = (const float*)d_in[9];
    const float* att_dst1 = (const float*)d_in[10];
    const float* bias1    = (const float*)d_in[11];
    const float* W2       = (const float*)d_in[12];
    const float* att_src2 = (const float*)d_in[13];
    const float* att_dst2 = (const float*)d_in[14];
    const float* bias2    = (const float*)d_in[15];

    // workspace layout (16B aligned), total ~95 MiB
    unsigned short* xg   = (unsigned short*)d_ws;            // 4,096,000 ush
    unsigned short* W1T  = xg + (size_t)2 * NS1 * F_IN;      //   196,608
    unsigned short* wswd = W1T + (size_t)K1 * F_IN;          //     4,096
    unsigned short* agg  = wswd + (size_t)32 * F_IN;         // 24,576,000
    float* es  = (float*)(agg + (size_t)2 * ND1 * K1);       //   384,000 f32
    float* ed  = es + (size_t)2 * NS1 * HEADS;               //   384,000
    float* s2  = ed + (size_t)2 * NS1 * HEADS;               //    16,000
    int* dcnt  = (int*)(s2 + (size_t)2 * ND1);               // 12,000 (g1|g2)
    int* srcp2 = dcnt + (ND1 + ND2);                         // 256,000 (g2)
    unsigned* ew = (unsigned*)(srcp2 + ND2 * CAP2 + 2);      // 8,192,000 u32
    ew = (unsigned*)(((size_t)ew + 15) & ~(size_t)15);       // 16B align

    // 1) fused prep (convA + convB + ws + zero dcnt/s2)
    k_prep<<<4894, 256, 0, stream>>>(x, n_id1, W1, att_src1, att_dst1,
                                     xg, W1T, wswd, dcnt, s2);

    // 2) scores (MFMA)
    k_escore<<<500, 256, 0, stream>>>(xg, wswd, es, ed);

    // 3) bucket scatter + per-edge weights (count fused via atomic slot)
    k_scatter2<<<(E1 + E2 + 255) / 256, 256, 0, stream>>>(
        dst1, src1, dst2, src2, res_n_id1, es, ed, dcnt, ew, srcp2);

    // 4) layer-1 aggregate in F space (one wave per (dst,b) task)
    k_agg1<<<MROWS / 4, 256, 0, stream>>>(xg, ew, dcnt, agg);

    // 5) projection + bias + relu + dot(W2), atomically into s2
    k_out1<<<dim3(MROWS / 128, HEADS), 256, 0, stream>>>(agg, W1T, bias1, W2, s2);

    // 6) layer-2
    k_agg2<<<(2 * ND2 + 255) / 256, 256, 0, stream>>>(s2, dcnt + ND1, srcp2,
                                                      res_n_id2, att_src2,
                                                      att_dst2, bias2,
                                                      (float*)d_out);
}